// Round 1
// baseline (635.632 us; speedup 1.0000x reference)
//
#include <hip/hip_runtime.h>

// GraphSAGE 3-layer forward, fp32.
// Pipeline per launch:
//   1. deg[dst]++ (atomics)        2. one-block exclusive scan -> off/pos/inv_deg
//   3. CSR fill (atomic slot)      4. per layer: gather(mean) + combine(matmul)
// N=50000, E=800000, dims all 128.

#define D 128

__global__ void k_init_deg(int* __restrict__ deg, int N) {
  int i = blockIdx.x * blockDim.x + threadIdx.x;
  if (i < N) deg[i] = 0;
}

__global__ void k_degree(const int* __restrict__ dst, int* __restrict__ deg, int E) {
  int e = blockIdx.x * blockDim.x + threadIdx.x;
  if (e < E) atomicAdd(&deg[dst[e]], 1);
}

// Single-block scan: deg -> exclusive prefix (off, pos), plus inv_deg.
__global__ __launch_bounds__(1024) void k_scan(const int* __restrict__ deg,
                                               int* __restrict__ off,
                                               int* __restrict__ pos,
                                               float* __restrict__ inv_deg,
                                               int N) {
  __shared__ int part[1024];
  int t = threadIdx.x;
  int C = (N + 1023) >> 10;
  int lo = t * C;
  int hi = min(lo + C, N);
  int s = 0;
  for (int i = lo; i < hi; ++i) s += deg[i];
  part[t] = s;
  __syncthreads();
  // Hillis-Steele inclusive scan over 1024 partials
  for (int d = 1; d < 1024; d <<= 1) {
    int v = part[t];
    int add = (t >= d) ? part[t - d] : 0;
    __syncthreads();
    part[t] = v + add;
    __syncthreads();
  }
  int run = (t == 0) ? 0 : part[t - 1];
  for (int i = lo; i < hi; ++i) {
    off[i] = run;
    pos[i] = run;
    int d = deg[i];
    inv_deg[i] = (d > 0) ? (1.0f / (float)d) : 0.0f;
    run += d;
  }
  if (t == 1023) off[N] = run;  // == E
}

__global__ void k_fill(const int* __restrict__ src, const int* __restrict__ dst,
                       int* __restrict__ pos, int* __restrict__ srcs, int E) {
  int e = blockIdx.x * blockDim.x + threadIdx.x;
  if (e < E) {
    int slot = atomicAdd(&pos[dst[e]], 1);
    srcs[slot] = src[e];
  }
}

// 32 threads per node, each owns 4 contiguous features (float4).
__global__ void k_gather(const float* __restrict__ hin, const int* __restrict__ off,
                         const int* __restrict__ srcs, const float* __restrict__ inv_deg,
                         float* __restrict__ meanb, int N) {
  int t = blockIdx.x * blockDim.x + threadIdx.x;
  int n = t >> 5;
  if (n >= N) return;
  int c = (t & 31) * 4;
  int lo = off[n], hi = off[n + 1];
  float4 acc = make_float4(0.f, 0.f, 0.f, 0.f);
  for (int e = lo; e < hi; ++e) {
    int s = srcs[e];
    const float4 v = *reinterpret_cast<const float4*>(hin + (size_t)s * D + c);
    acc.x += v.x; acc.y += v.y; acc.z += v.z; acc.w += v.w;
  }
  float w = inv_deg[n];
  acc.x *= w; acc.y *= w; acc.z *= w; acc.w *= w;
  *reinterpret_cast<float4*>(meanb + (size_t)n * D + c) = acc;
}

// out[n,f] = b[f] + mean[n,:]@Wl[:,f] + hin[n,:]@Wr[:,f], optional relu.
// Tile: 64 nodes x 128 cols per block (512 threads); thread = 4 nodes x 4 cols.
// Rows (mean+h) staged in 64KB LDS; weights stream from L1/L2 as float4.
template <int RELU>
__global__ __launch_bounds__(512) void k_combine(const float* __restrict__ hin,
                                                 const float* __restrict__ meanb,
                                                 const float* __restrict__ Wl,
                                                 const float* __restrict__ Wr,
                                                 const float* __restrict__ bias,
                                                 float* __restrict__ hout, int N) {
  __shared__ float rows[64][256];  // [node][0..127]=mean, [128..255]=h
  int tid = threadIdx.x;
  int node0 = blockIdx.x * 64;

  for (int i = tid; i < 64 * 64; i += 512) {  // 4096 float4 slots
    int nl = i >> 6;
    int s = i & 63;
    int n = node0 + nl;
    float4 v = make_float4(0.f, 0.f, 0.f, 0.f);
    if (n < N) {
      v = (s < 32) ? *reinterpret_cast<const float4*>(meanb + (size_t)n * D + s * 4)
                   : *reinterpret_cast<const float4*>(hin + (size_t)n * D + (s - 32) * 4);
    }
    *reinterpret_cast<float4*>(&rows[nl][s * 4]) = v;
  }
  __syncthreads();

  int f4 = (tid & 31) * 4;  // column group
  int g = tid >> 5;         // node group 0..15 -> nodes g*4..g*4+3
  float4 bv = *reinterpret_cast<const float4*>(bias + f4);
  float4 acc[4] = {bv, bv, bv, bv};

#pragma unroll 2
  for (int k = 0; k < 128; ++k) {
    float4 wl = *reinterpret_cast<const float4*>(Wl + k * D + f4);
    float4 wr = *reinterpret_cast<const float4*>(Wr + k * D + f4);
#pragma unroll
    for (int j = 0; j < 4; ++j) {
      float m = rows[g * 4 + j][k];
      float h = rows[g * 4 + j][128 + k];
      acc[j].x = fmaf(m, wl.x, fmaf(h, wr.x, acc[j].x));
      acc[j].y = fmaf(m, wl.y, fmaf(h, wr.y, acc[j].y));
      acc[j].z = fmaf(m, wl.z, fmaf(h, wr.z, acc[j].z));
      acc[j].w = fmaf(m, wl.w, fmaf(h, wr.w, acc[j].w));
    }
  }

#pragma unroll
  for (int j = 0; j < 4; ++j) {
    int n = node0 + g * 4 + j;
    if (n < N) {
      float4 o = acc[j];
      if (RELU) {
        o.x = fmaxf(o.x, 0.f); o.y = fmaxf(o.y, 0.f);
        o.z = fmaxf(o.z, 0.f); o.w = fmaxf(o.w, 0.f);
      }
      *reinterpret_cast<float4*>(hout + (size_t)n * D + f4) = o;
    }
  }
}

extern "C" void kernel_launch(void* const* d_in, const int* in_sizes, int n_in,
                              void* d_out, int out_size, void* d_ws, size_t ws_size,
                              hipStream_t stream) {
  const float* x   = (const float*)d_in[0];
  const int*   ei  = (const int*)d_in[1];
  const float* Wl1 = (const float*)d_in[2];
  const float* b1  = (const float*)d_in[3];
  const float* Wr1 = (const float*)d_in[4];
  const float* Wl2 = (const float*)d_in[5];
  const float* b2  = (const float*)d_in[6];
  const float* Wr2 = (const float*)d_in[7];
  const float* Wl3 = (const float*)d_in[8];
  const float* b3  = (const float*)d_in[9];
  const float* Wr3 = (const float*)d_in[10];
  float* out = (float*)d_out;

  int N = in_sizes[0] / D;
  int E = in_sizes[1] / 2;
  const int* srcp = ei;
  const int* dstp = ei + E;

  char* p = (char*)d_ws;
  auto carve = [&](size_t bytes) {
    void* r = (void*)p;
    p += (bytes + 255) & ~(size_t)255;
    return r;
  };
  int*   deg   = (int*)carve((size_t)N * 4);
  int*   pos   = (int*)carve((size_t)N * 4);
  int*   off   = (int*)carve((size_t)(N + 1) * 4);
  float* invd  = (float*)carve((size_t)N * 4);
  int*   srcs  = (int*)carve((size_t)E * 4);
  float* meanb = (float*)carve((size_t)N * D * 4);
  float* h1    = (float*)carve((size_t)N * D * 4);
  float* h2    = (float*)carve((size_t)N * D * 4);

  // --- CSR build ---
  k_init_deg<<<(N + 255) / 256, 256, 0, stream>>>(deg, N);
  k_degree<<<(E + 255) / 256, 256, 0, stream>>>(dstp, deg, E);
  k_scan<<<1, 1024, 0, stream>>>(deg, off, pos, invd, N);
  k_fill<<<(E + 255) / 256, 256, 0, stream>>>(srcp, dstp, pos, srcs, E);

  int gather_blocks  = (N * 32 + 255) / 256;
  int combine_blocks = (N + 63) / 64;

  // --- layer 1: x -> h1 (relu) ---
  k_gather<<<gather_blocks, 256, 0, stream>>>(x, off, srcs, invd, meanb, N);
  k_combine<1><<<combine_blocks, 512, 0, stream>>>(x, meanb, Wl1, Wr1, b1, h1, N);
  // --- layer 2: h1 -> h2 (relu) ---
  k_gather<<<gather_blocks, 256, 0, stream>>>(h1, off, srcs, invd, meanb, N);
  k_combine<1><<<combine_blocks, 512, 0, stream>>>(h1, meanb, Wl2, Wr2, b2, h2, N);
  // --- layer 3: h2 -> out (no relu) ---
  k_gather<<<gather_blocks, 256, 0, stream>>>(h2, off, srcs, invd, meanb, N);
  k_combine<0><<<combine_blocks, 512, 0, stream>>>(h2, meanb, Wl3, Wr3, b3, out, N);
}

// Round 2
// 507.770 us; speedup vs baseline: 1.2518x; 1.2518x over previous
//
#include <hip/hip_runtime.h>

// GraphSAGE 3-layer forward, fp32.
// Pipeline per launch:
//   1. deg[dst]++ (atomics)
//   2. 3-kernel device-wide exclusive scan -> off/pos/inv_deg  (R1: was 1-block, 133us)
//   3. CSR fill (atomic slot)
//   4. per layer: gather(mean) + combine(matmul)
// N=50000, E=800000, dims all 128.

#define D 128

__global__ void k_init_deg(int* __restrict__ deg, int N) {
  int i = blockIdx.x * blockDim.x + threadIdx.x;
  if (i < N) deg[i] = 0;
}

__global__ void k_degree(const int* __restrict__ dst, int* __restrict__ deg, int E) {
  int e = blockIdx.x * blockDim.x + threadIdx.x;
  if (e < E) atomicAdd(&deg[dst[e]], 1);
}

// ---- scan stage 1: per-block (1024 elems) sums ----
__global__ __launch_bounds__(256) void k_block_sums(const int* __restrict__ deg,
                                                    int* __restrict__ bsum, int N) {
  __shared__ int part[256];
  int t = threadIdx.x;
  int base = blockIdx.x * 1024 + t * 4;
  int s = 0;
  if (base + 3 < N) {
    const int4 v = *reinterpret_cast<const int4*>(deg + base);
    s = v.x + v.y + v.z + v.w;
  } else {
    for (int i = 0; i < 4; ++i)
      if (base + i < N) s += deg[base + i];
  }
  part[t] = s;
  __syncthreads();
  for (int d = 128; d > 0; d >>= 1) {
    if (t < d) part[t] += part[t + d];
    __syncthreads();
  }
  if (t == 0) bsum[blockIdx.x] = part[0];
}

// ---- scan stage 2: exclusive-scan the (<=1024) block sums; write off[N]=E ----
__global__ __launch_bounds__(1024) void k_scan_bsums(int* __restrict__ bsum,
                                                     int* __restrict__ offN, int nblk) {
  __shared__ int part[1024];
  int t = threadIdx.x;
  part[t] = (t < nblk) ? bsum[t] : 0;
  __syncthreads();
  for (int d = 1; d < 1024; d <<= 1) {
    int x = part[t];
    int add = (t >= d) ? part[t - d] : 0;
    __syncthreads();
    part[t] = x + add;
    __syncthreads();
  }
  if (t < nblk) bsum[t] = (t == 0) ? 0 : part[t - 1];
  if (t == nblk - 1) *offN = part[t];
}

// ---- scan stage 3: local re-scan + base, emit off/pos/inv_deg ----
__global__ __launch_bounds__(256) void k_scan_apply(const int* __restrict__ deg,
                                                    const int* __restrict__ bsum,
                                                    int* __restrict__ off,
                                                    int* __restrict__ pos,
                                                    float* __restrict__ invd, int N) {
  __shared__ int part[256];
  int t = threadIdx.x;
  int base = blockIdx.x * 1024 + t * 4;
  int d0 = 0, d1 = 0, d2 = 0, d3 = 0;
  if (base + 3 < N) {
    const int4 v = *reinterpret_cast<const int4*>(deg + base);
    d0 = v.x; d1 = v.y; d2 = v.z; d3 = v.w;
  } else {
    if (base < N) d0 = deg[base];
    if (base + 1 < N) d1 = deg[base + 1];
    if (base + 2 < N) d2 = deg[base + 2];
    if (base + 3 < N) d3 = deg[base + 3];
  }
  part[t] = d0 + d1 + d2 + d3;
  __syncthreads();
  for (int d = 1; d < 256; d <<= 1) {
    int x = part[t];
    int add = (t >= d) ? part[t - d] : 0;
    __syncthreads();
    part[t] = x + add;
    __syncthreads();
  }
  int run = bsum[blockIdx.x] + ((t == 0) ? 0 : part[t - 1]);
  int offs[4] = {run, run + d0, run + d0 + d1, run + d0 + d1 + d2};
  int degs[4] = {d0, d1, d2, d3};
#pragma unroll
  for (int i = 0; i < 4; ++i) {
    int idx = base + i;
    if (idx < N) {
      off[idx] = offs[i];
      pos[idx] = offs[i];
      invd[idx] = degs[i] > 0 ? 1.0f / (float)degs[i] : 0.0f;
    }
  }
}

__global__ void k_fill(const int* __restrict__ src, const int* __restrict__ dst,
                       int* __restrict__ pos, int* __restrict__ srcs, int E) {
  int e = blockIdx.x * blockDim.x + threadIdx.x;
  if (e < E) {
    int slot = atomicAdd(&pos[dst[e]], 1);
    srcs[slot] = src[e];
  }
}

// 32 threads per node, each owns 4 contiguous features (float4).
__global__ void k_gather(const float* __restrict__ hin, const int* __restrict__ off,
                         const int* __restrict__ srcs, const float* __restrict__ inv_deg,
                         float* __restrict__ meanb, int N) {
  int t = blockIdx.x * blockDim.x + threadIdx.x;
  int n = t >> 5;
  if (n >= N) return;
  int c = (t & 31) * 4;
  int lo = off[n], hi = off[n + 1];
  float4 acc = make_float4(0.f, 0.f, 0.f, 0.f);
  for (int e = lo; e < hi; ++e) {
    int s = srcs[e];
    const float4 v = *reinterpret_cast<const float4*>(hin + (size_t)s * D + c);
    acc.x += v.x; acc.y += v.y; acc.z += v.z; acc.w += v.w;
  }
  float w = inv_deg[n];
  acc.x *= w; acc.y *= w; acc.z *= w; acc.w *= w;
  *reinterpret_cast<float4*>(meanb + (size_t)n * D + c) = acc;
}

// out[n,f] = b[f] + mean[n,:]@Wl[:,f] + hin[n,:]@Wr[:,f], optional relu.
// Tile: 64 nodes x 128 cols per block (512 threads); thread = 4 nodes x 4 cols.
template <int RELU>
__global__ __launch_bounds__(512) void k_combine(const float* __restrict__ hin,
                                                 const float* __restrict__ meanb,
                                                 const float* __restrict__ Wl,
                                                 const float* __restrict__ Wr,
                                                 const float* __restrict__ bias,
                                                 float* __restrict__ hout, int N) {
  __shared__ float rows[64][256];  // [node][0..127]=mean, [128..255]=h
  int tid = threadIdx.x;
  int node0 = blockIdx.x * 64;

  for (int i = tid; i < 64 * 64; i += 512) {  // 4096 float4 slots
    int nl = i >> 6;
    int s = i & 63;
    int n = node0 + nl;
    float4 v = make_float4(0.f, 0.f, 0.f, 0.f);
    if (n < N) {
      v = (s < 32) ? *reinterpret_cast<const float4*>(meanb + (size_t)n * D + s * 4)
                   : *reinterpret_cast<const float4*>(hin + (size_t)n * D + (s - 32) * 4);
    }
    *reinterpret_cast<float4*>(&rows[nl][s * 4]) = v;
  }
  __syncthreads();

  int f4 = (tid & 31) * 4;  // column group
  int g = tid >> 5;         // node group 0..15 -> nodes g*4..g*4+3
  float4 bv = *reinterpret_cast<const float4*>(bias + f4);
  float4 acc[4] = {bv, bv, bv, bv};

#pragma unroll 2
  for (int k = 0; k < 128; ++k) {
    float4 wl = *reinterpret_cast<const float4*>(Wl + k * D + f4);
    float4 wr = *reinterpret_cast<const float4*>(Wr + k * D + f4);
#pragma unroll
    for (int j = 0; j < 4; ++j) {
      float m = rows[g * 4 + j][k];
      float h = rows[g * 4 + j][128 + k];
      acc[j].x = fmaf(m, wl.x, fmaf(h, wr.x, acc[j].x));
      acc[j].y = fmaf(m, wl.y, fmaf(h, wr.y, acc[j].y));
      acc[j].z = fmaf(m, wl.z, fmaf(h, wr.z, acc[j].z));
      acc[j].w = fmaf(m, wl.w, fmaf(h, wr.w, acc[j].w));
    }
  }

#pragma unroll
  for (int j = 0; j < 4; ++j) {
    int n = node0 + g * 4 + j;
    if (n < N) {
      float4 o = acc[j];
      if (RELU) {
        o.x = fmaxf(o.x, 0.f); o.y = fmaxf(o.y, 0.f);
        o.z = fmaxf(o.z, 0.f); o.w = fmaxf(o.w, 0.f);
      }
      *reinterpret_cast<float4*>(hout + (size_t)n * D + f4) = o;
    }
  }
}

extern "C" void kernel_launch(void* const* d_in, const int* in_sizes, int n_in,
                              void* d_out, int out_size, void* d_ws, size_t ws_size,
                              hipStream_t stream) {
  const float* x   = (const float*)d_in[0];
  const int*   ei  = (const int*)d_in[1];
  const float* Wl1 = (const float*)d_in[2];
  const float* b1  = (const float*)d_in[3];
  const float* Wr1 = (const float*)d_in[4];
  const float* Wl2 = (const float*)d_in[5];
  const float* b2  = (const float*)d_in[6];
  const float* Wr2 = (const float*)d_in[7];
  const float* Wl3 = (const float*)d_in[8];
  const float* b3  = (const float*)d_in[9];
  const float* Wr3 = (const float*)d_in[10];
  float* out = (float*)d_out;

  int N = in_sizes[0] / D;
  int E = in_sizes[1] / 2;
  const int* srcp = ei;
  const int* dstp = ei + E;

  char* p = (char*)d_ws;
  auto carve = [&](size_t bytes) {
    void* r = (void*)p;
    p += (bytes + 255) & ~(size_t)255;
    return r;
  };
  int*   deg   = (int*)carve((size_t)N * 4);
  int*   pos   = (int*)carve((size_t)N * 4);
  int*   off   = (int*)carve((size_t)(N + 1) * 4);
  float* invd  = (float*)carve((size_t)N * 4);
  int*   srcs  = (int*)carve((size_t)E * 4);
  int*   bsum  = (int*)carve((size_t)1024 * 4);
  float* meanb = (float*)carve((size_t)N * D * 4);
  float* h1    = (float*)carve((size_t)N * D * 4);
  float* h2    = (float*)carve((size_t)N * D * 4);

  int nblk = (N + 1023) / 1024;  // 49

  // --- CSR build ---
  k_init_deg<<<(N + 255) / 256, 256, 0, stream>>>(deg, N);
  k_degree<<<(E + 255) / 256, 256, 0, stream>>>(dstp, deg, E);
  k_block_sums<<<nblk, 256, 0, stream>>>(deg, bsum, N);
  k_scan_bsums<<<1, 1024, 0, stream>>>(bsum, off + N, nblk);
  k_scan_apply<<<nblk, 256, 0, stream>>>(deg, bsum, off, pos, invd, N);
  k_fill<<<(E + 255) / 256, 256, 0, stream>>>(srcp, dstp, pos, srcs, E);

  int gather_blocks  = (N * 32 + 255) / 256;
  int combine_blocks = (N + 63) / 64;

  // --- layer 1: x -> h1 (relu) ---
  k_gather<<<gather_blocks, 256, 0, stream>>>(x, off, srcs, invd, meanb, N);
  k_combine<1><<<combine_blocks, 512, 0, stream>>>(x, meanb, Wl1, Wr1, b1, h1, N);
  // --- layer 2: h1 -> h2 (relu) ---
  k_gather<<<gather_blocks, 256, 0, stream>>>(h1, off, srcs, invd, meanb, N);
  k_combine<1><<<combine_blocks, 512, 0, stream>>>(h1, meanb, Wl2, Wr2, b2, h2, N);
  // --- layer 3: h2 -> out (no relu) ---
  k_gather<<<gather_blocks, 256, 0, stream>>>(h2, off, srcs, invd, meanb, N);
  k_combine<0><<<combine_blocks, 512, 0, stream>>>(h2, meanb, Wl3, Wr3, b3, out, N);
}

// Round 3
// 279.973 us; speedup vs baseline: 2.2703x; 1.8136x over previous
//
#include <hip/hip_runtime.h>

// GraphSAGE 3-layer forward. CSR build (fp32/int) + bf16 feature pipeline:
//   x --cast--> xb(bf16); per layer: gather-mean (bf16 in, fp32 acc, bf16 out)
//   then MFMA combine: C[M,128] = [mean|h](bf16) @ [Wl;Wr](bf16) + b, fp32 acc.
// Weights pre-packed into per-lane MFMA fragment order (no LDS in combine).
// N=50000, E=800000, D=128, K=256.

#define D 128

typedef __attribute__((ext_vector_type(8))) short bf16x8;
typedef __attribute__((ext_vector_type(4))) float f32x4;

__device__ inline ushort f2bf(float f) {
  union { float f; unsigned u; } v; v.f = f;
  unsigned r = v.u + 0x7fffu + ((v.u >> 16) & 1u);
  return (ushort)(r >> 16);
}
__device__ inline float bf2f(ushort h) {
  union { unsigned u; float f; } v; v.u = ((unsigned)h) << 16;
  return v.f;
}

__global__ void k_init_deg(int* __restrict__ deg, int N) {
  int i = blockIdx.x * blockDim.x + threadIdx.x;
  if (i < N) deg[i] = 0;
}

__global__ void k_degree(const int* __restrict__ dst, int* __restrict__ deg, int E) {
  int e = blockIdx.x * blockDim.x + threadIdx.x;
  if (e < E) atomicAdd(&deg[dst[e]], 1);
}

__global__ __launch_bounds__(256) void k_block_sums(const int* __restrict__ deg,
                                                    int* __restrict__ bsum, int N) {
  __shared__ int part[256];
  int t = threadIdx.x;
  int base = blockIdx.x * 1024 + t * 4;
  int s = 0;
  if (base + 3 < N) {
    const int4 v = *reinterpret_cast<const int4*>(deg + base);
    s = v.x + v.y + v.z + v.w;
  } else {
    for (int i = 0; i < 4; ++i)
      if (base + i < N) s += deg[base + i];
  }
  part[t] = s;
  __syncthreads();
  for (int d = 128; d > 0; d >>= 1) {
    if (t < d) part[t] += part[t + d];
    __syncthreads();
  }
  if (t == 0) bsum[blockIdx.x] = part[0];
}

__global__ __launch_bounds__(1024) void k_scan_bsums(int* __restrict__ bsum,
                                                     int* __restrict__ offN, int nblk) {
  __shared__ int part[1024];
  int t = threadIdx.x;
  part[t] = (t < nblk) ? bsum[t] : 0;
  __syncthreads();
  for (int d = 1; d < 1024; d <<= 1) {
    int x = part[t];
    int add = (t >= d) ? part[t - d] : 0;
    __syncthreads();
    part[t] = x + add;
    __syncthreads();
  }
  if (t < nblk) bsum[t] = (t == 0) ? 0 : part[t - 1];
  if (t == nblk - 1) *offN = part[t];
}

__global__ __launch_bounds__(256) void k_scan_apply(const int* __restrict__ deg,
                                                    const int* __restrict__ bsum,
                                                    int* __restrict__ off,
                                                    int* __restrict__ pos,
                                                    float* __restrict__ invd, int N) {
  __shared__ int part[256];
  int t = threadIdx.x;
  int base = blockIdx.x * 1024 + t * 4;
  int d0 = 0, d1 = 0, d2 = 0, d3 = 0;
  if (base + 3 < N) {
    const int4 v = *reinterpret_cast<const int4*>(deg + base);
    d0 = v.x; d1 = v.y; d2 = v.z; d3 = v.w;
  } else {
    if (base < N) d0 = deg[base];
    if (base + 1 < N) d1 = deg[base + 1];
    if (base + 2 < N) d2 = deg[base + 2];
    if (base + 3 < N) d3 = deg[base + 3];
  }
  part[t] = d0 + d1 + d2 + d3;
  __syncthreads();
  for (int d = 1; d < 256; d <<= 1) {
    int x = part[t];
    int add = (t >= d) ? part[t - d] : 0;
    __syncthreads();
    part[t] = x + add;
    __syncthreads();
  }
  int run = bsum[blockIdx.x] + ((t == 0) ? 0 : part[t - 1]);
  int offs[4] = {run, run + d0, run + d0 + d1, run + d0 + d1 + d2};
  int degs[4] = {d0, d1, d2, d3};
#pragma unroll
  for (int i = 0; i < 4; ++i) {
    int idx = base + i;
    if (idx < N) {
      off[idx] = offs[i];
      pos[idx] = offs[i];
      invd[idx] = degs[i] > 0 ? 1.0f / (float)degs[i] : 0.0f;
    }
  }
}

__global__ void k_fill(const int* __restrict__ src, const int* __restrict__ dst,
                       int* __restrict__ pos, int* __restrict__ srcs, int E) {
  int e = blockIdx.x * blockDim.x + threadIdx.x;
  if (e < E) {
    int slot = atomicAdd(&pos[dst[e]], 1);
    srcs[slot] = src[e];
  }
}

// fp32 -> bf16 cast, 4 elems/thread
__global__ void k_cast(const float* __restrict__ x, ushort* __restrict__ xb, int total4) {
  int i = blockIdx.x * blockDim.x + threadIdx.x;
  if (i >= total4) return;
  float4 v = *reinterpret_cast<const float4*>(x + (size_t)i * 4);
  ushort4 o;
  o.x = f2bf(v.x); o.y = f2bf(v.y); o.z = f2bf(v.z); o.w = f2bf(v.w);
  *reinterpret_cast<ushort4*>(xb + (size_t)i * 4) = o;
}

// Pack [Wl;Wr] (fp32, K=256 x 128) into per-lane MFMA B-fragment order, bf16:
// element idx = ((kk*8+ct)*64 + lane)*8 + j  holds  B[kk*32+(lane>>4)*8+j][ct*16+(lane&15)]
__global__ void k_pack(const float* __restrict__ Wl, const float* __restrict__ Wr,
                       ushort* __restrict__ Bp) {
  int idx = blockIdx.x * blockDim.x + threadIdx.x;  // 32768 total
  int kk = idx >> 12;
  int ct = (idx >> 9) & 7;
  int l  = (idx >> 3) & 63;
  int j  = idx & 7;
  int k = kk * 32 + ((l >> 4) << 3) + j;
  int col = ct * 16 + (l & 15);
  float v = (k < 128) ? Wl[k * 128 + col] : Wr[(k - 128) * 128 + col];
  Bp[idx] = f2bf(v);
}

// 16 lanes per node, each owns 8 bf16 features (16B loads). fp32 accumulate.
__global__ void k_gather(const ushort* __restrict__ hin, const int* __restrict__ off,
                         const int* __restrict__ srcs, const float* __restrict__ invd,
                         ushort* __restrict__ meanb, int N) {
  int t = blockIdx.x * blockDim.x + threadIdx.x;
  int n = t >> 4;
  if (n >= N) return;
  int c = (t & 15) * 8;
  int lo = off[n], hi = off[n + 1];
  float acc[8] = {0.f, 0.f, 0.f, 0.f, 0.f, 0.f, 0.f, 0.f};
  for (int e = lo; e < hi; ++e) {
    int s = srcs[e];
    bf16x8 v = *reinterpret_cast<const bf16x8*>(hin + (size_t)s * D + c);
#pragma unroll
    for (int j = 0; j < 8; ++j) acc[j] += bf2f((ushort)v[j]);
  }
  float w = invd[n];
  bf16x8 ov;
#pragma unroll
  for (int j = 0; j < 8; ++j) ov[j] = (short)f2bf(acc[j] * w);
  *reinterpret_cast<bf16x8*>(meanb + (size_t)n * D + c) = ov;
}

// MFMA combine: block = 256 thr = 4 waves; wave w owns rows [row0+w*16, +16).
// Each wave: 8 col-tiles x 8 k-steps of mfma_f32_16x16x32_bf16.
// A-frag: lane holds A[row0+w*16+(l&15)][kk*32+(l>>4)*8 + 0..7] (16B global load).
// B-frag: pre-packed, lane loads 16B at ((kk*8+ct)*64+l)*8.
// C/D: row=(l>>4)*4+reg, col=ct*16+(l&15)  [m89-verified layout]
template <int RELU, int FINAL>
__global__ __launch_bounds__(256) void k_combine(const ushort* __restrict__ meanb,
                                                 const ushort* __restrict__ hb,
                                                 const ushort* __restrict__ Bpack,
                                                 const float* __restrict__ bias,
                                                 float* __restrict__ outf,
                                                 ushort* __restrict__ outh, int N) {
  int l = threadIdx.x & 63;
  int w = threadIdx.x >> 6;
  int row0 = blockIdx.x * 64 + w * 16;
  int lr = l & 15;
  int kgrp = l >> 4;
  int arow = row0 + lr;
  if (arow >= N) arow = N - 1;  // clamp loads; stores guarded
  size_t abase = (size_t)arow * D;

  f32x4 acc[8];
#pragma unroll
  for (int ct = 0; ct < 8; ++ct) {
    float bv = bias[ct * 16 + lr];
    acc[ct] = (f32x4){bv, bv, bv, bv};
  }

#pragma unroll
  for (int kk = 0; kk < 8; ++kk) {
    const ushort* asrc = (kk < 4) ? meanb : hb;
    int klocal = ((kk & 3) << 5) + (kgrp << 3);
    bf16x8 a = *reinterpret_cast<const bf16x8*>(asrc + abase + klocal);
    const ushort* bb = Bpack + ((size_t)kk << 12) + ((size_t)l << 3);
#pragma unroll
    for (int ct = 0; ct < 8; ++ct) {
      bf16x8 b = *reinterpret_cast<const bf16x8*>(bb + (ct << 9));
      acc[ct] = __builtin_amdgcn_mfma_f32_16x16x32_bf16(a, b, acc[ct], 0, 0, 0);
    }
  }

#pragma unroll
  for (int ct = 0; ct < 8; ++ct) {
    int c = ct * 16 + lr;
#pragma unroll
    for (int r = 0; r < 4; ++r) {
      int rr = row0 + kgrp * 4 + r;
      if (rr < N) {
        float v = acc[ct][r];
        if (RELU) v = fmaxf(v, 0.f);
        if (FINAL) outf[(size_t)rr * D + c] = v;
        else outh[(size_t)rr * D + c] = f2bf(v);
      }
    }
  }
}

extern "C" void kernel_launch(void* const* d_in, const int* in_sizes, int n_in,
                              void* d_out, int out_size, void* d_ws, size_t ws_size,
                              hipStream_t stream) {
  const float* x   = (const float*)d_in[0];
  const int*   ei  = (const int*)d_in[1];
  const float* Wl1 = (const float*)d_in[2];
  const float* b1  = (const float*)d_in[3];
  const float* Wr1 = (const float*)d_in[4];
  const float* Wl2 = (const float*)d_in[5];
  const float* b2  = (const float*)d_in[6];
  const float* Wr2 = (const float*)d_in[7];
  const float* Wl3 = (const float*)d_in[8];
  const float* b3  = (const float*)d_in[9];
  const float* Wr3 = (const float*)d_in[10];
  float* out = (float*)d_out;

  int N = in_sizes[0] / D;
  int E = in_sizes[1] / 2;
  const int* srcp = ei;
  const int* dstp = ei + E;

  char* p = (char*)d_ws;
  auto carve = [&](size_t bytes) {
    void* r = (void*)p;
    p += (bytes + 255) & ~(size_t)255;
    return r;
  };
  int*    deg   = (int*)carve((size_t)N * 4);
  int*    pos   = (int*)carve((size_t)N * 4);
  int*    off   = (int*)carve((size_t)(N + 1) * 4);
  float*  invd  = (float*)carve((size_t)N * 4);
  int*    srcs  = (int*)carve((size_t)E * 4);
  int*    bsum  = (int*)carve((size_t)1024 * 4);
  ushort* xb    = (ushort*)carve((size_t)N * D * 2);
  ushort* h1b   = (ushort*)carve((size_t)N * D * 2);
  ushort* h2b   = (ushort*)carve((size_t)N * D * 2);
  ushort* meanb = (ushort*)carve((size_t)N * D * 2);
  ushort* Bp1   = (ushort*)carve((size_t)32768 * 2);
  ushort* Bp2   = (ushort*)carve((size_t)32768 * 2);
  ushort* Bp3   = (ushort*)carve((size_t)32768 * 2);

  int nblk = (N + 1023) / 1024;

  // --- CSR build ---
  k_init_deg<<<(N + 255) / 256, 256, 0, stream>>>(deg, N);
  k_degree<<<(E + 255) / 256, 256, 0, stream>>>(dstp, deg, E);
  k_block_sums<<<nblk, 256, 0, stream>>>(deg, bsum, N);
  k_scan_bsums<<<1, 1024, 0, stream>>>(bsum, off + N, nblk);
  k_scan_apply<<<nblk, 256, 0, stream>>>(deg, bsum, off, pos, invd, N);
  k_fill<<<(E + 255) / 256, 256, 0, stream>>>(srcp, dstp, pos, srcs, E);

  // --- casts + weight packing ---
  int total4 = N * D / 4;
  k_cast<<<(total4 + 255) / 256, 256, 0, stream>>>(x, xb, total4);
  k_pack<<<32768 / 256, 256, 0, stream>>>(Wl1, Wr1, Bp1);
  k_pack<<<32768 / 256, 256, 0, stream>>>(Wl2, Wr2, Bp2);
  k_pack<<<32768 / 256, 256, 0, stream>>>(Wl3, Wr3, Bp3);

  int gather_blocks  = (N * 16 + 255) / 256;
  int combine_blocks = (N + 63) / 64;

  // --- layer 1: xb -> h1b (relu) ---
  k_gather<<<gather_blocks, 256, 0, stream>>>(xb, off, srcs, invd, meanb, N);
  k_combine<1, 0><<<combine_blocks, 256, 0, stream>>>(meanb, xb, Bp1, b1, nullptr, h1b, N);
  // --- layer 2: h1b -> h2b (relu) ---
  k_gather<<<gather_blocks, 256, 0, stream>>>(h1b, off, srcs, invd, meanb, N);
  k_combine<1, 0><<<combine_blocks, 256, 0, stream>>>(meanb, h1b, Bp2, b2, nullptr, h2b, N);
  // --- layer 3: h2b -> out (fp32, no relu) ---
  k_gather<<<gather_blocks, 256, 0, stream>>>(h2b, off, srcs, invd, meanb, N);
  k_combine<0, 1><<<combine_blocks, 256, 0, stream>>>(meanb, h2b, Bp3, b3, out, nullptr, N);
}

// Round 4
// 219.820 us; speedup vs baseline: 2.8916x; 1.2736x over previous
//
#include <hip/hip_runtime.h>

// GraphSAGE 3-layer forward.
// CSR build via 2-level bucketing (R4: replaces degree-atomics + scan + scatter
// fill whose 4B random stores cost 52MB of line-granular HBM writes):
//   bucket = dst>>7 (128 nodes/bucket).
//   k_bhist: LDS-agg bucket histogram -> k_bscan: bucket bases ->
//   k_bucket: partition packed (src<<16|dst) into bucket regions (coalesced runs) ->
//   k_csr: per-bucket per-dst count + LDS scan -> off/invd/srcs (region-local writes).
// Feature pipeline (bf16): cast x; per layer gather-mean then MFMA combine
// (mfma_f32_16x16x32_bf16, weights pre-packed in fragment order).
// N=50000, E=800000, D=128, K=256.  Requires N <= 65536 (16-bit packing).

#define D 128

typedef __attribute__((ext_vector_type(8))) short bf16x8;
typedef __attribute__((ext_vector_type(4))) float f32x4;

__device__ inline ushort f2bf(float f) {
  union { float f; unsigned u; } v; v.f = f;
  unsigned r = v.u + 0x7fffu + ((v.u >> 16) & 1u);
  return (ushort)(r >> 16);
}
__device__ inline float bf2f(ushort h) {
  union { unsigned u; float f; } v; v.u = ((unsigned)h) << 16;
  return v.f;
}

// ---- CSR stage 1: global bucket histogram (LDS-aggregated) ----
__global__ __launch_bounds__(256) void k_bhist(const int* __restrict__ dst,
                                               int* __restrict__ bhist, int E, int NB) {
  __shared__ int h[512];
  int t = threadIdx.x;
  for (int i = t; i < NB; i += 256) h[i] = 0;
  __syncthreads();
  int beg = blockIdx.x * 4096;
  int end = min(beg + 4096, E);
  for (int i = beg + t; i < end; i += 256) atomicAdd(&h[dst[i] >> 7], 1);
  __syncthreads();
  for (int i = t; i < NB; i += 256)
    if (h[i]) atomicAdd(&bhist[i], h[i]);
}

// ---- CSR stage 2: scan bucket counts -> bases; init cursors; off[N]=E ----
__global__ __launch_bounds__(512) void k_bscan(const int* __restrict__ bhist,
                                               int* __restrict__ bbase,
                                               int* __restrict__ bcur,
                                               int* __restrict__ offN, int NB) {
  __shared__ int part[512];
  int t = threadIdx.x;
  part[t] = (t < NB) ? bhist[t] : 0;
  __syncthreads();
  for (int d = 1; d < 512; d <<= 1) {
    int x = part[t];
    int a = (t >= d) ? part[t - d] : 0;
    __syncthreads();
    part[t] = x + a;
    __syncthreads();
  }
  if (t < NB) {
    int b = (t == 0) ? 0 : part[t - 1];
    bbase[t] = b;
    bcur[t] = b;
  }
  if (t == NB - 1) *offN = part[t];
}

// ---- CSR stage 3: partition edges into bucket regions (packed u32) ----
__global__ __launch_bounds__(256) void k_bucket(const int* __restrict__ src,
                                                const int* __restrict__ dst,
                                                int* __restrict__ bcur,
                                                unsigned* __restrict__ ebuf,
                                                int E, int NB) {
  __shared__ int h[512];
  __shared__ int base[512];
  int t = threadIdx.x;
  for (int i = t; i < NB; i += 256) h[i] = 0;
  __syncthreads();
  int beg = blockIdx.x * 4096;
  int end = min(beg + 4096, E);
  for (int i = beg + t; i < end; i += 256) atomicAdd(&h[dst[i] >> 7], 1);
  __syncthreads();
  for (int i = t; i < NB; i += 256) {
    int c = h[i];
    base[i] = c ? atomicAdd(&bcur[i], c) : 0;
    h[i] = 0;
  }
  __syncthreads();
  for (int i = beg + t; i < end; i += 256) {
    int d = dst[i];
    int b = d >> 7;
    int r = atomicAdd(&h[b], 1);
    ebuf[base[b] + r] = (((unsigned)src[i]) << 16) | (unsigned)d;
  }
}

// ---- CSR stage 4: per-bucket per-dst CSR (one block per bucket) ----
__global__ __launch_bounds__(256) void k_csr(const unsigned* __restrict__ ebuf,
                                             const int* __restrict__ bbase,
                                             const int* __restrict__ bhist,
                                             int* __restrict__ off,
                                             float* __restrict__ invd,
                                             int* __restrict__ srcs, int N) {
  __shared__ int dcount[128];
  __shared__ int dloc[128];
  int b = blockIdx.x;
  int t = threadIdx.x;
  int beg = bbase[b];
  int end = beg + bhist[b];
  if (t < 128) dcount[t] = 0;
  __syncthreads();
  for (int i = beg + t; i < end; i += 256) atomicAdd(&dcount[ebuf[i] & 127], 1);
  __syncthreads();
  if (t < 128) dloc[t] = dcount[t];
  __syncthreads();
  for (int d = 1; d < 128; d <<= 1) {
    int x = 0, a = 0;
    if (t < 128) {
      x = dloc[t];
      if (t >= d) a = dloc[t - d];
    }
    __syncthreads();
    if (t < 128) dloc[t] = x + a;
    __syncthreads();
  }
  if (t < 128) {
    int node = b * 128 + t;
    if (node < N) {
      int ex = beg + dloc[t] - dcount[t];
      off[node] = ex;
      int c = dcount[t];
      invd[node] = c > 0 ? 1.0f / (float)c : 0.0f;
      dcount[t] = ex;  // becomes cursor
    }
  }
  __syncthreads();
  for (int i = beg + t; i < end; i += 256) {
    unsigned p = ebuf[i];
    int slot = atomicAdd(&dcount[p & 127], 1);
    srcs[slot] = (int)(p >> 16);
  }
}

// ---- fp32 -> bf16 cast, 4 elems/thread ----
__global__ void k_cast(const float* __restrict__ x, ushort* __restrict__ xb, int total4) {
  int i = blockIdx.x * blockDim.x + threadIdx.x;
  if (i >= total4) return;
  float4 v = *reinterpret_cast<const float4*>(x + (size_t)i * 4);
  ushort4 o;
  o.x = f2bf(v.x); o.y = f2bf(v.y); o.z = f2bf(v.z); o.w = f2bf(v.w);
  *reinterpret_cast<ushort4*>(xb + (size_t)i * 4) = o;
}

// ---- pack all 3 layers' [Wl;Wr] into MFMA B-fragment order, bf16 ----
// Per layer: element idx = ((kk*8+ct)*64 + lane)*8 + j holds
//   B[kk*32+(lane>>4)*8+j][ct*16+(lane&15)]   (B = [Wl;Wr], K=256 x 128)
__global__ void k_pack3(const float* __restrict__ Wl1, const float* __restrict__ Wr1,
                        const float* __restrict__ Wl2, const float* __restrict__ Wr2,
                        const float* __restrict__ Wl3, const float* __restrict__ Wr3,
                        ushort* __restrict__ Bp) {
  int gidx = blockIdx.x * blockDim.x + threadIdx.x;  // 3*32768 total
  int layer = gidx >> 15;
  int idx = gidx & 32767;
  const float* Wl = (layer == 0) ? Wl1 : (layer == 1) ? Wl2 : Wl3;
  const float* Wr = (layer == 0) ? Wr1 : (layer == 1) ? Wr2 : Wr3;
  int kk = idx >> 12;
  int ct = (idx >> 9) & 7;
  int l  = (idx >> 3) & 63;
  int j  = idx & 7;
  int k = kk * 32 + ((l >> 4) << 3) + j;
  int col = ct * 16 + (l & 15);
  float v = (k < 128) ? Wl[k * 128 + col] : Wr[(k - 128) * 128 + col];
  Bp[gidx] = f2bf(v);
}

// ---- gather-mean: 16 lanes per node, each owns 8 bf16 features ----
__global__ void k_gather(const ushort* __restrict__ hin, const int* __restrict__ off,
                         const int* __restrict__ srcs, const float* __restrict__ invd,
                         ushort* __restrict__ meanb, int N) {
  int t = blockIdx.x * blockDim.x + threadIdx.x;
  int n = t >> 4;
  if (n >= N) return;
  int c = (t & 15) * 8;
  int lo = off[n], hi = off[n + 1];
  float acc[8] = {0.f, 0.f, 0.f, 0.f, 0.f, 0.f, 0.f, 0.f};
  for (int e = lo; e < hi; ++e) {
    int s = srcs[e];
    bf16x8 v = *reinterpret_cast<const bf16x8*>(hin + (size_t)s * D + c);
#pragma unroll
    for (int j = 0; j < 8; ++j) acc[j] += bf2f((ushort)v[j]);
  }
  float w = invd[n];
  bf16x8 ov;
#pragma unroll
  for (int j = 0; j < 8; ++j) ov[j] = (short)f2bf(acc[j] * w);
  *reinterpret_cast<bf16x8*>(meanb + (size_t)n * D + c) = ov;
}

// ---- MFMA combine: block = 256 thr = 4 waves; wave w owns rows [row0+w*16,+16) ----
// A-frag: lane holds A[row0+w*16+(l&15)][kk*32+(l>>4)*8 + 0..7] (16B global load).
// B-frag: pre-packed, lane loads 16B at ((kk*8+ct)*64+l)*8.
// C/D: row=(l>>4)*4+reg, col=ct*16+(l&15)  [m89-verified layout]
template <int RELU, int FINAL>
__global__ __launch_bounds__(256) void k_combine(const ushort* __restrict__ meanb,
                                                 const ushort* __restrict__ hb,
                                                 const ushort* __restrict__ Bpack,
                                                 const float* __restrict__ bias,
                                                 float* __restrict__ outf,
                                                 ushort* __restrict__ outh, int N) {
  int l = threadIdx.x & 63;
  int w = threadIdx.x >> 6;
  int row0 = blockIdx.x * 64 + w * 16;
  int lr = l & 15;
  int kgrp = l >> 4;
  int arow = row0 + lr;
  if (arow >= N) arow = N - 1;  // clamp loads; stores guarded
  size_t abase = (size_t)arow * D;

  f32x4 acc[8];
#pragma unroll
  for (int ct = 0; ct < 8; ++ct) {
    float bv = bias[ct * 16 + lr];
    acc[ct] = (f32x4){bv, bv, bv, bv};
  }

#pragma unroll
  for (int kk = 0; kk < 8; ++kk) {
    const ushort* asrc = (kk < 4) ? meanb : hb;
    int klocal = ((kk & 3) << 5) + (kgrp << 3);
    bf16x8 a = *reinterpret_cast<const bf16x8*>(asrc + abase + klocal);
    const ushort* bb = Bpack + ((size_t)kk << 12) + ((size_t)l << 3);
#pragma unroll
    for (int ct = 0; ct < 8; ++ct) {
      bf16x8 b = *reinterpret_cast<const bf16x8*>(bb + (ct << 9));
      acc[ct] = __builtin_amdgcn_mfma_f32_16x16x32_bf16(a, b, acc[ct], 0, 0, 0);
    }
  }

#pragma unroll
  for (int ct = 0; ct < 8; ++ct) {
    int c = ct * 16 + lr;
#pragma unroll
    for (int r = 0; r < 4; ++r) {
      int rr = row0 + kgrp * 4 + r;
      if (rr < N) {
        float v = acc[ct][r];
        if (RELU) v = fmaxf(v, 0.f);
        if (FINAL) outf[(size_t)rr * D + c] = v;
        else outh[(size_t)rr * D + c] = f2bf(v);
      }
    }
  }
}

extern "C" void kernel_launch(void* const* d_in, const int* in_sizes, int n_in,
                              void* d_out, int out_size, void* d_ws, size_t ws_size,
                              hipStream_t stream) {
  const float* x   = (const float*)d_in[0];
  const int*   ei  = (const int*)d_in[1];
  const float* Wl1 = (const float*)d_in[2];
  const float* b1  = (const float*)d_in[3];
  const float* Wr1 = (const float*)d_in[4];
  const float* Wl2 = (const float*)d_in[5];
  const float* b2  = (const float*)d_in[6];
  const float* Wr2 = (const float*)d_in[7];
  const float* Wl3 = (const float*)d_in[8];
  const float* b3  = (const float*)d_in[9];
  const float* Wr3 = (const float*)d_in[10];
  float* out = (float*)d_out;

  int N = in_sizes[0] / D;
  int E = in_sizes[1] / 2;
  const int* srcp = ei;
  const int* dstp = ei + E;
  int NB = (N + 127) >> 7;  // 391 for N=50000

  char* p = (char*)d_ws;
  auto carve = [&](size_t bytes) {
    void* r = (void*)p;
    p += (bytes + 255) & ~(size_t)255;
    return r;
  };
  int*      bhist = (int*)carve((size_t)512 * 4);
  int*      bbase = (int*)carve((size_t)512 * 4);
  int*      bcur  = (int*)carve((size_t)512 * 4);
  int*      off   = (int*)carve((size_t)(N + 1) * 4);
  float*    invd  = (float*)carve((size_t)N * 4);
  int*      srcs  = (int*)carve((size_t)E * 4);
  unsigned* ebuf  = (unsigned*)carve((size_t)E * 4);
  ushort*   xb    = (ushort*)carve((size_t)N * D * 2);
  ushort*   h1b   = (ushort*)carve((size_t)N * D * 2);
  ushort*   h2b   = (ushort*)carve((size_t)N * D * 2);
  ushort*   meanb = (ushort*)carve((size_t)N * D * 2);
  ushort*   Bp    = (ushort*)carve((size_t)3 * 32768 * 2);

  // --- CSR build (bucketed) ---
  hipMemsetAsync(bhist, 0, (size_t)NB * 4, stream);
  int ch_blocks = (E + 4095) / 4096;
  k_bhist<<<ch_blocks, 256, 0, stream>>>(dstp, bhist, E, NB);
  k_bscan<<<1, 512, 0, stream>>>(bhist, bbase, bcur, off + N, NB);
  k_bucket<<<ch_blocks, 256, 0, stream>>>(srcp, dstp, bcur, ebuf, E, NB);
  k_csr<<<NB, 256, 0, stream>>>(ebuf, bbase, bhist, off, invd, srcs, N);

  // --- casts + weight packing ---
  int total4 = N * D / 4;
  k_cast<<<(total4 + 255) / 256, 256, 0, stream>>>(x, xb, total4);
  k_pack3<<<3 * 32768 / 256, 256, 0, stream>>>(Wl1, Wr1, Wl2, Wr2, Wl3, Wr3, Bp);

  int gather_blocks  = (N * 16 + 255) / 256;
  int combine_blocks = (N + 63) / 64;

  // --- layer 1: xb -> h1b (relu) ---
  k_gather<<<gather_blocks, 256, 0, stream>>>(xb, off, srcs, invd, meanb, N);
  k_combine<1, 0><<<combine_blocks, 256, 0, stream>>>(meanb, xb, Bp, b1, nullptr, h1b, N);
  // --- layer 2: h1b -> h2b (relu) ---
  k_gather<<<gather_blocks, 256, 0, stream>>>(h1b, off, srcs, invd, meanb, N);
  k_combine<1, 0><<<combine_blocks, 256, 0, stream>>>(meanb, h1b, Bp + 32768, b2, nullptr, h2b, N);
  // --- layer 3: h2b -> out (fp32, no relu) ---
  k_gather<<<gather_blocks, 256, 0, stream>>>(h2b, off, srcs, invd, meanb, N);
  k_combine<0, 1><<<combine_blocks, 256, 0, stream>>>(meanb, h2b, Bp + 2 * 32768, b3, out, nullptr, N);
}